// Round 21
// baseline (106.206 us; speedup 1.0000x reference)
//
#include <hip/hip_runtime.h>
#include <math.h>

#define NB 4
#define NS 2048
#define ND 256
#define NH 8
#define NHD 32
#define NFF 1024
#define NM (NB*NS)   // 8192
#define KPAD 40      // K-tile LDS row stride (bf16)
#define VSP 72       // Vt-tile LDS row stride (bf16)
#define VTP 72       // Ex row stride (epilogue O-bounce)
#define AS 264       // gemm A-tile LDS row stride (bf16 elems)
// qkv Q pre-scale: (1/sqrt(32)) * log2(e)  -> softmax uses exp2, no max subtraction
#define QSCALE 0.2550181657f

typedef __attribute__((ext_vector_type(4))) short short4v;
typedef __attribute__((ext_vector_type(8))) short short8v;
typedef __attribute__((ext_vector_type(4))) float f32x4;
typedef unsigned short us;

__device__ __forceinline__ us f2bf(float f){
  union { float f; unsigned u; } c; c.f = f;
  unsigned u = c.u + 0x7fffu + ((c.u >> 16) & 1u);   // RNE
  return (us)(u >> 16);
}

__device__ __forceinline__ float wsum(float v){
  #pragma unroll
  for(int o=32;o>0;o>>=1) v += __shfl_xor(v,o);
  return v;
}

// fragment-major offset: M'[(row>>4)][k>>5][lane=lw*16+lx][8 elems]
__device__ __forceinline__ size_t frag_off(unsigned n, unsigned kk8, unsigned K){
  return (size_t)(n >> 4)*(16u*K) + (size_t)(kk8 >> 2)*512u + (size_t)(((kk8 & 3u)*16u + (n & 15u))*8u);
}

// ---------------- prep: weights fp32 -> bf16 fragment-major (Wq/bq pre-scaled) ----------------
__global__ __launch_bounds__(256) void prep_kernel(
    const float* __restrict__ Wq, const float* __restrict__ Wk, const float* __restrict__ Wv,
    const float* __restrict__ Wo, const float* __restrict__ W1, const float* __restrict__ W2,
    const float* __restrict__ bq,
    us* __restrict__ Wqkvb, us* __restrict__ Wob,
    us* __restrict__ W1b, us* __restrict__ W2b, float* __restrict__ bqs){
  unsigned bid = blockIdx.x;
  if (bid == 384){ bqs[threadIdx.x] = bq[threadIdx.x]*QSCALE; return; }
  unsigned v = bid*256u + threadIdx.x;     // 8-elem unit, 98304 total
  const float* sp; us* dp; float sc = 1.f;
  if (v < 8192u){                 // Wq (256x256)
    unsigned u = v, n = u>>5, kk8 = u&31u;
    sp = Wq + (size_t)u*8; dp = Wqkvb + frag_off(n, kk8, 256); sc = QSCALE;
  } else if (v < 16384u){         // Wk
    unsigned u = v-8192u, n = u>>5, kk8 = u&31u;
    sp = Wk + (size_t)u*8; dp = Wqkvb + 65536 + frag_off(n, kk8, 256);
  } else if (v < 24576u){         // Wv
    unsigned u = v-16384u, n = u>>5, kk8 = u&31u;
    sp = Wv + (size_t)u*8; dp = Wqkvb + 131072 + frag_off(n, kk8, 256);
  } else if (v < 32768u){         // Wo (256x256)
    unsigned u = v-24576u, n = u>>5, kk8 = u&31u;
    sp = Wo + (size_t)u*8; dp = Wob + frag_off(n, kk8, 256);
  } else if (v < 65536u){         // W1 (1024x256)
    unsigned u = v-32768u, n = u>>5, kk8 = u&31u;
    sp = W1 + (size_t)u*8; dp = W1b + frag_off(n, kk8, 256);
  } else {                        // W2 (256x1024)
    unsigned u = v-65536u, n = u>>7, kk8 = u&127u;
    sp = W2 + (size_t)u*8; dp = W2b + frag_off(n, kk8, 1024);
  }
  float4 a = *(const float4*)sp, b = *(const float4*)(sp+4);
  short8v o;
  o[0]=(short)f2bf(a.x*sc); o[1]=(short)f2bf(a.y*sc); o[2]=(short)f2bf(a.z*sc); o[3]=(short)f2bf(a.w*sc);
  o[4]=(short)f2bf(b.x*sc); o[5]=(short)f2bf(b.y*sc); o[6]=(short)f2bf(b.z*sc); o[7]=(short)f2bf(b.w*sc);
  *(short8v*)dp = o;
}

// ---------------- generic MFMA GEMM: C[M][N] = A[M][KTOT] @ W[N][KTOT]^T (+bias, epilogue) ----------------
// W is fragment-major (coalesced 1KB wave loads). tile: M=64 x N=128 (4 waves, each 64x32).
// AF32=1: A read from fp32 (Af) and converted during staging.
// EPI: 0 = qkv -> Q,K row-major bf16 + V transposed bf16; 1/3 = +resid(f32) -> f32
template<int KTOT, int EPI, int AF32>
__global__ __launch_bounds__(256) void gemm_kernel(
    const us* __restrict__ A, const float* __restrict__ Af,
    const us* __restrict__ W,
    const float* __restrict__ bias0, const float* __restrict__ bias1, const float* __restrict__ bias2,
    const float* __restrict__ resid,
    us* __restrict__ outb, us* __restrict__ outv, float* __restrict__ outf){
  __shared__ us Asl[64*AS];
  const int t = threadIdx.x, l = t&63, wv = t>>6;
  const int lx = l&15, lw = l>>4;
  const int m0 = blockIdx.y*64;
  const int n0 = blockIdx.x*128 + wv*32;

  f32x4 acc[4][2];
  #pragma unroll
  for(int mb=0;mb<4;mb++)
    #pragma unroll
    for(int nb=0;nb<2;nb++) acc[mb][nb] = (f32x4){0.f,0.f,0.f,0.f};

  for (int kc = 0; kc < KTOT; kc += 256){
    __syncthreads();
    if (AF32){
      #pragma unroll
      for (int it=0; it<16; it++){
        int idx = it*256 + t;          // 4096 float4 units: 64 rows x 64
        int r = idx>>6, c = idx&63;
        float4 v = *(const float4*)(Af + (size_t)(m0+r)*KTOT + kc + c*4);
        short4v o4 = { (short)f2bf(v.x),(short)f2bf(v.y),(short)f2bf(v.z),(short)f2bf(v.w) };
        *(short4v*)&Asl[r*AS + c*4] = o4;
      }
    } else {
      #pragma unroll
      for (int it=0; it<8; it++){
        int idx = it*256 + t;          // 2048 16B-units: 64 rows x 32
        int r = idx>>5, c = idx&31;
        *(short8v*)&Asl[r*AS + c*8] = *(const short8v*)(A + (size_t)(m0+r)*KTOT + kc + c*8);
      }
    }
    __syncthreads();
    short8v bf[2][8];
    #pragma unroll
    for (int nb=0; nb<2; nb++)
      #pragma unroll
      for (int ks=0; ks<8; ks++)
        bf[nb][ks] = *(const short8v*)(W + (size_t)(n0 + nb*16)*KTOT + kc*16 + ks*512 + l*8);
    #pragma unroll
    for (int ks=0; ks<8; ks++){
      short8v af[4];
      #pragma unroll
      for (int mb=0; mb<4; mb++)
        af[mb] = *(const short8v*)&Asl[(mb*16+lx)*AS + ks*32 + 8*lw];
      #pragma unroll
      for (int mb=0; mb<4; mb++){
        acc[mb][0] = __builtin_amdgcn_mfma_f32_16x16x32_bf16(af[mb], bf[0][ks], acc[mb][0], 0,0,0);
        acc[mb][1] = __builtin_amdgcn_mfma_f32_16x16x32_bf16(af[mb], bf[1][ks], acc[mb][1], 0,0,0);
      }
    }
  }
  // epilogue: lane l, reg r -> m = m0 + mb*16 + 4*lw + r, n = n0 + nb*16 + lx
  const int mr0 = m0 + 4*lw;
  #pragma unroll
  for (int nb=0; nb<2; nb++){
    int n = n0 + nb*16 + lx;
    if (EPI == 0){
      int seg = n >> 8, nn = n & 255;
      const float* bp = (seg==0) ? bias0 : (seg==1) ? bias1 : bias2;
      float bb = bp[nn];
      if (seg < 2){
        us* op = outb + (size_t)seg*((size_t)NM*ND) + nn;
        #pragma unroll
        for (int mb=0; mb<4; mb++)
          #pragma unroll
          for (int r=0; r<4; r++)
            op[(size_t)(mr0 + mb*16 + r)*ND] = f2bf(acc[mb][nb][r] + bb);
      } else {   // V: write transposed Vt[b][h][d][s]
        int hh = nn >> 5, dd = nn & 31;
        int bidx = mr0 >> 11;           // batch (uniform per block)
        int s0 = mr0 & 2047;
        us* vp = outv + (((size_t)bidx*NH + hh)*NHD + dd)*NS;
        #pragma unroll
        for (int mb=0; mb<4; mb++){
          short4v v4;
          #pragma unroll
          for (int r=0; r<4; r++) v4[r] = (short)f2bf(acc[mb][nb][r] + bb);
          *(short4v*)(vp + s0 + mb*16) = v4;
        }
      }
    } else {   // EPI 1/3: +resid(f32) -> f32
      float bb = bias0[n];
      #pragma unroll
      for (int mb=0; mb<4; mb++)
        #pragma unroll
        for (int r=0; r<4; r++){
          size_t off = (size_t)(mr0 + mb*16 + r)*ND + n;
          outf[off] = acc[mb][nb][r] + bb + resid[off];
        }
    }
  }
}

// ---------------- ffn1 direct-fragment: zero LDS, zero barriers ----------------
// A (S2b) and W both fragment-major; per wave: 32 A-frag + 32 W-frag coalesced 1KB loads,
// 128 MFMAs, fully independent waves. tile M=64 x N=256 (4 waves x 64x64), grid (4,128).
__global__ __launch_bounds__(256) void ffn1w_kernel(
    const us* __restrict__ Afrag, const us* __restrict__ W,
    const float* __restrict__ bias, us* __restrict__ FF){
  const int t = threadIdx.x, l = t&63, wv = t>>6;
  const int lx = l&15, lw = l>>4;
  const int m0 = blockIdx.y*64;
  const int n0 = blockIdx.x*256 + wv*64;

  f32x4 acc[4][4];
  #pragma unroll
  for(int mb=0;mb<4;mb++)
    #pragma unroll
    for(int nb=0;nb<4;nb++) acc[mb][nb] = (f32x4){0.f,0.f,0.f,0.f};

  #pragma unroll
  for (int ks=0; ks<8; ks++){
    short8v af[4], bf[4];
    #pragma unroll
    for (int mb=0; mb<4; mb++)
      af[mb] = *(const short8v*)(Afrag + (size_t)(m0 + mb*16)*ND + ks*512 + l*8);
    #pragma unroll
    for (int nb=0; nb<4; nb++)
      bf[nb] = *(const short8v*)(W + (size_t)(n0 + nb*16)*ND + ks*512 + l*8);
    #pragma unroll
    for (int mb=0; mb<4; mb++)
      #pragma unroll
      for (int nb=0; nb<4; nb++)
        acc[mb][nb] = __builtin_amdgcn_mfma_f32_16x16x32_bf16(af[mb], bf[nb], acc[mb][nb], 0,0,0);
  }
  const int mr0 = m0 + 4*lw;
  #pragma unroll
  for (int nb=0; nb<4; nb++){
    int n = n0 + nb*16 + lx;
    float bb = bias[n];
    #pragma unroll
    for (int mb=0; mb<4; mb++)
      #pragma unroll
      for (int r=0; r<4; r++){
        float x = acc[mb][nb][r] + bb;
        float g = 0.5f*x*(1.f + erff(x*0.70710678118654752f));
        FF[(size_t)(mr0 + mb*16 + r)*NFF + n] = f2bf(g);
      }
  }
}

// ---------------- standalone LayerNorm: fp32 in -> bf16 frag-major (optional) + fp32 (optional) ----------------
__global__ __launch_bounds__(256) void ln_kernel(
    const float* __restrict__ Xin, const float* __restrict__ g, const float* __restrict__ be,
    us* __restrict__ outb_frag, float* __restrict__ outf){
  const int t = threadIdx.x, lane = t&63, wv = t>>6;
  const int m0 = blockIdx.x*16;
  #pragma unroll
  for(int rr=0; rr<4; rr++){
    int r = m0 + wv*4 + rr;
    const float* xr = Xin + (size_t)r*ND;
    float x[4]; float s=0.f,q=0.f;
    #pragma unroll
    for(int k=0;k<4;k++){ x[k]=xr[lane+64*k]; s+=x[k]; q+=x[k]*x[k]; }
    s = wsum(s); q = wsum(q);
    float mean = s*(1.f/ND), var = q*(1.f/ND)-mean*mean;
    float rstd = rsqrtf(var+1e-5f);
    #pragma unroll
    for(int k=0;k<4;k++){
      int col = lane+64*k;
      float y = (x[k]-mean)*rstd*g[col] + be[col];
      if (outf) outf[(size_t)r*ND+col] = y;
      if (outb_frag) outb_frag[frag_off((unsigned)r, (unsigned)(col>>3), 256) + (col&7)] = f2bf(y);
    }
  }
}

// ---------------- attention tile body: lane-local P (permuted-V LDS), tree lsum ----------------
// V LDS layout per 32-key block: slot(16m+4a+b) = 8a+4m+b  (a=0..3,m=0..1,b=0..3).
// PV B-frag slot j at lane (lx,lw) needs key 32c+16(j>>2)+4lw+(j&3) == this lane's p[8c+j].
template<bool MASK>
__device__ __forceinline__ void attn_tile(
    const us* __restrict__ Kl, const us* __restrict__ Vl,
    const short8v qf, const int lx, const int lw, const int jt, const int qg,
    f32x4& acc0, f32x4& acc1, float& lsum){
  f32x4 s4[4];
  #pragma unroll
  for (int kb=0; kb<4; kb++){
    short8v kf = *(const short8v*)(Kl + (kb*16 + lx)*KPAD + 8*lw);
    f32x4 z = {0.f,0.f,0.f,0.f};
    s4[kb] = __builtin_amdgcn_mfma_f32_16x16x32_bf16(kf, qf, z, 0,0,0);
  }
  float p[16];
  #pragma unroll
  for (int kb=0; kb<4; kb++)
    #pragma unroll
    for (int r=0; r<4; r++){
      float x = exp2f(s4[kb][r]);
      if (MASK) x = ((jt + 16*kb + 4*lw + r) > qg) ? 0.f : x;
      p[kb*4+r] = x;
    }
  {
    float a0=p[0]+p[1],   a1=p[2]+p[3],   a2=p[4]+p[5],   a3=p[6]+p[7];
    float a4=p[8]+p[9],   a5=p[10]+p[11], a6=p[12]+p[13], a7=p[14]+p[15];
    float b0=a0+a1, b1=a2+a3, b2=a4+a5, b3=a6+a7;
    lsum += (b0+b1) + (b2+b3);
  }
  #pragma unroll
  for (int c=0; c<2; c++){
    unsigned w0,w1,w2,w3;
    asm("v_cvt_pk_bf16_f32 %0, %1, %2" : "=v"(w0) : "v"(p[8*c+0]), "v"(p[8*c+1]));
    asm("v_cvt_pk_bf16_f32 %0, %1, %2" : "=v"(w1) : "v"(p[8*c+2]), "v"(p[8*c+3]));
    asm("v_cvt_pk_bf16_f32 %0, %1, %2" : "=v"(w2) : "v"(p[8*c+4]), "v"(p[8*c+5]));
    asm("v_cvt_pk_bf16_f32 %0, %1, %2" : "=v"(w3) : "v"(p[8*c+6]), "v"(p[8*c+7]));
    union { unsigned u[4]; short8v v; } pu;
    pu.u[0]=w0; pu.u[1]=w1; pu.u[2]=w2; pu.u[3]=w3;
    short8v pf = pu.v;
    short8v aL = *(const short8v*)(Vl + (size_t)( lx    )*VSP + 32*c + 8*lw);
    short8v aH = *(const short8v*)(Vl + (size_t)(16+lx  )*VSP + 32*c + 8*lw);
    acc0 = __builtin_amdgcn_mfma_f32_16x16x32_bf16(aL, pf, acc0, 0,0,0);
    acc1 = __builtin_amdgcn_mfma_f32_16x16x32_bf16(aH, pf, acc1, 0,0,0);
  }
}

// ---------------- MFMA flash attention: dbuf LDS staging, 1 barrier/tile, lane-local P ----------------
__global__ __launch_bounds__(256) void attn_kernel(
    const us* __restrict__ Q, const us* __restrict__ K,
    const us* __restrict__ Vt, us* __restrict__ AO){
  __shared__ us Klds[2][64*KPAD];      // 2 x 5120 B
  __shared__ us Vs[2][32*VSP];         // 2 x 4608 B  (permuted slot layout)
  __shared__ us Ex[4][16*VTP];         // 4 x 2304 B  per-wave O-bounce (epilogue only)

  const int t = threadIdx.x, l = t & 63, wv = t >> 6;
  const int lx = l & 15, lw = l >> 4;
  const int bid = blockIdx.x;
  const int qtile = 31 - (bid >> 5);   // biggest query tiles first
  const int bh = bid & 31;
  const int b = bh >> 3, h = bh & 7;
  const int qbase = qtile*64 + wv*16;  // this wave's first query
  const int qg = qbase + lx;

  const us* Qg = Q + ((size_t)b*NS)*ND + h*NHD;
  const us* Kg = K + ((size_t)b*NS)*ND + h*NHD;
  const us* Vg = Vt + (size_t)bh*NHD*NS;

  short8v qf = *(const short8v*)(Qg + (size_t)(qbase + lx)*ND + 8*lw);

  f32x4 acc0 = {0.f,0.f,0.f,0.f}, acc1 = {0.f,0.f,0.f,0.f};
  float lsum = 0.f;

  const int kr = t >> 2, kp = t & 3;   // K staging: 64 rows x 4 b128 segs
  const int vd = t >> 3, vp = t & 7;   // V staging: 32 d-rows x 8 key-segs
  const int vS0 = 32*(vp>>2) + 16*(vp&1) + 4*((vp>>1)&1);   // permuted slot base
  const int jmax = qtile*64;           // final (masked) tile start

  // prologue: stage tile 0
  {
    short8v k0 = *(const short8v*)(Kg + (size_t)kr*ND + kp*8);
    short8v v0 = *(const short8v*)(Vg + (size_t)vd*NS + vp*8);
    *(short8v*)&Klds[0][kr*KPAD + kp*8] = k0;
    short4v lo = {v0[0],v0[1],v0[2],v0[3]}, hi = {v0[4],v0[5],v0[6],v0[7]};
    *(short4v*)&Vs[0][vd*VSP + vS0]     = lo;
    *(short4v*)&Vs[0][vd*VSP + vS0 + 8] = hi;
  }
  __syncthreads();

  int cur = 0;
  for (int jt = 0; jt < jmax; jt += 64){
    short8v kn = *(const short8v*)(Kg + (size_t)(jt + 64 + kr)*ND + kp*8);
    short8v vn = *(const short8v*)(Vg + (size_t)vd*NS + (jt + 64) + vp*8);
    attn_tile<false>(&Klds[cur][0], &Vs[cur][0], qf, lx, lw, jt, qg, acc0, acc1, lsum);
    *(short8v*)&Klds[cur^1][kr*KPAD + kp*8] = kn;
    short4v lo = {vn[0],vn[1],vn[2],vn[3]}, hi = {vn[4],vn[5],vn[6],vn[7]};
    *(short4v*)&Vs[cur^1][vd*VSP + vS0]     = lo;
    *(short4v*)&Vs[cur^1][vd*VSP + vS0 + 8] = hi;
    __syncthreads();
    cur ^= 1;
  }
  // final tile (diagonal): causal mask, no prefetch
  attn_tile<true>(&Klds[cur][0], &Vs[cur][0], qf, lx, lw, jmax, qg, acc0, acc1, lsum);

  // epilogue: normalize, bounce O^T->O through per-wave LDS, bf16 store
  float lt = lsum + __shfl_xor(lsum, 16);
  lt += __shfl_xor(lt, 32);
  float inv = 1.f / lt;
  float* ol = (float*)&Ex[wv][0];
  #pragma unroll
  for (int r=0;r<4;r++){
    ol[lx*36 +      4*lw + r] = acc0[r]*inv;
    ol[lx*36 + 16 + 4*lw + r] = acc1[r]*inv;
  }
  int rr = l >> 2, cc = l & 3;         // 16 rows x 4 chunks of 8
  const float* op8 = &ol[rr*36 + cc*8];
  short8v o8;
  #pragma unroll
  for (int j=0;j<8;j++) o8[j] = (short)f2bf(op8[j]);
  *(short8v*)(AO + ((size_t)(b*NS + qbase + rr))*ND + h*NHD + cc*8) = o8;
}

extern "C" void kernel_launch(void* const* d_in, const int* in_sizes, int n_in,
                              void* d_out, int out_size, void* d_ws, size_t ws_size,
                              hipStream_t stream){
  const float* src = (const float*)d_in[0];
  const float* Wq  = (const float*)d_in[1];
  const float* bq  = (const float*)d_in[2];
  const float* Wk  = (const float*)d_in[3];
  const float* bk  = (const float*)d_in[4];
  const float* Wv  = (const float*)d_in[5];
  const float* bv  = (const float*)d_in[6];
  const float* Wo  = (const float*)d_in[7];
  const float* bo  = (const float*)d_in[8];
  const float* W1  = (const float*)d_in[9];
  const float* b1  = (const float*)d_in[10];
  const float* W2  = (const float*)d_in[11];
  const float* b2  = (const float*)d_in[12];
  const float* g1  = (const float*)d_in[13];
  const float* be1 = (const float*)d_in[14];
  const float* g2  = (const float*)d_in[15];
  const float* be2 = (const float*)d_in[16];
  // len_m1 (d_in[17]) is redundant: the prefix-global mask is implied by causal.

  const size_t MB = 1048576;
  unsigned char* w8 = (unsigned char*)d_ws;
  us* Qb    = (us*)(w8 + 4*MB);        // 4MB, dead after attn
  us* Kb    = (us*)(w8 + 8*MB);
  us* Vtg   = (us*)(w8 + 12*MB);       // V transposed [b][h][d][s]
  us* AO    = (us*)(w8 + 16*MB);
  us* S2b   = (us*)(w8 + 20*MB);       // LN1 out bf16, fragment-major
  us* FF    = (us*)(w8 + 24*MB);       // 16MB
  us* Wqkvb = (us*)(w8 + 40*MB);       // 384KB  (fragment-major; Wq*QSCALE | Wk | Wv)
  us* Wob   = (us*)(w8 + 40*MB + 384*1024);
  us* W1b   = (us*)(w8 + 40*MB + 512*1024);
  us* W2b   = (us*)(w8 + 40*MB + 1024*1024);
  float* bqs   = (float*)(w8 + 40*MB + 1536*1024);
  float* S2pre = (float*)(w8 + 42*MB); // 8MB
  float* S2f   = (float*)(w8 + 50*MB); // 8MB
  float* Ypre  = (float*)(w8 + 0);     // 8MB at offset 0 (Qb dead by then)
  float* out = (float*)d_out;

  prep_kernel<<<385, 256, 0, stream>>>(Wq,Wk,Wv,Wo,W1,W2, bq, Wqkvb, Wob, W1b, W2b, bqs);
  gemm_kernel<256,0,1><<<dim3(6,128), 256, 0, stream>>>(nullptr, src, Wqkvb, bqs, bk, bv, nullptr, Qb, Vtg, nullptr);
  attn_kernel<<<1024, 256, 0, stream>>>(Qb, Kb, Vtg, AO);
  gemm_kernel<256,1,0><<<dim3(2,128), 256, 0, stream>>>(AO, nullptr, Wob, bo, nullptr, nullptr, src, nullptr, nullptr, S2pre);
  ln_kernel<<<NM/16, 256, 0, stream>>>(S2pre, g1, be1, S2b, S2f);
  ffn1w_kernel<<<dim3(4,128), 256, 0, stream>>>(S2b, W1b, b1, FF);
  gemm_kernel<1024,3,0><<<dim3(2,128), 256, 0, stream>>>(FF, nullptr, W2b, b2, nullptr, nullptr, S2f, nullptr, nullptr, Ypre);
  ln_kernel<<<NM/16, 256, 0, stream>>>(Ypre, g2, be2, nullptr, out);
}

// Round 22
// 98.260 us; speedup vs baseline: 1.0809x; 1.0809x over previous
//
#include <hip/hip_runtime.h>
#include <math.h>

#define NB 4
#define NS 2048
#define ND 256
#define NH 8
#define NHD 32
#define NFF 1024
#define NM (NB*NS)   // 8192
#define KPAD 40      // K-tile LDS row stride (bf16)
#define VSP 72       // Vt-tile LDS row stride (bf16)
#define VTP 72       // Ex row stride (epilogue O-bounce)
#define AS 264       // gemm A-tile LDS row stride (bf16 elems)
// qkv Q pre-scale: (1/sqrt(32)) * log2(e)  -> softmax uses exp2, no max subtraction
#define QSCALE 0.2550181657f

typedef __attribute__((ext_vector_type(4))) short short4v;
typedef __attribute__((ext_vector_type(8))) short short8v;
typedef __attribute__((ext_vector_type(4))) float f32x4;
typedef unsigned short us;

__device__ __forceinline__ us f2bf(float f){
  union { float f; unsigned u; } c; c.f = f;
  unsigned u = c.u + 0x7fffu + ((c.u >> 16) & 1u);   // RNE
  return (us)(u >> 16);
}
__device__ __forceinline__ float bf2f(us u){
  union { unsigned u; float f; } c; c.u = ((unsigned)u) << 16; return c.f;
}

__device__ __forceinline__ float wsum(float v){
  #pragma unroll
  for(int o=32;o>0;o>>=1) v += __shfl_xor(v,o);
  return v;
}

// fragment-major W offset: W'[(n>>4)][k>>5][lane=lw*16+lx][8 elems]
__device__ __forceinline__ size_t frag_off(unsigned n, unsigned kk8, unsigned K){
  return (size_t)(n >> 4)*(16u*K) + (size_t)(kk8 >> 2)*512u + (size_t)(((kk8 & 3u)*16u + (n & 15u))*8u);
}

// ---------------- prep: weights fp32 -> bf16 fragment-major (Wq/bq pre-scaled) ----------------
__global__ __launch_bounds__(256) void prep_kernel(
    const float* __restrict__ Wq, const float* __restrict__ Wk, const float* __restrict__ Wv,
    const float* __restrict__ Wo, const float* __restrict__ W1, const float* __restrict__ W2,
    const float* __restrict__ bq,
    us* __restrict__ Wqkvb, us* __restrict__ Wob,
    us* __restrict__ W1b, us* __restrict__ W2b, float* __restrict__ bqs){
  unsigned bid = blockIdx.x;
  if (bid == 384){ bqs[threadIdx.x] = bq[threadIdx.x]*QSCALE; return; }
  unsigned v = bid*256u + threadIdx.x;     // 8-elem unit, 98304 total
  const float* sp; us* dp; float sc = 1.f;
  if (v < 8192u){                 // Wq (256x256)
    unsigned u = v, n = u>>5, kk8 = u&31u;
    sp = Wq + (size_t)u*8; dp = Wqkvb + frag_off(n, kk8, 256); sc = QSCALE;
  } else if (v < 16384u){         // Wk
    unsigned u = v-8192u, n = u>>5, kk8 = u&31u;
    sp = Wk + (size_t)u*8; dp = Wqkvb + 65536 + frag_off(n, kk8, 256);
  } else if (v < 24576u){         // Wv
    unsigned u = v-16384u, n = u>>5, kk8 = u&31u;
    sp = Wv + (size_t)u*8; dp = Wqkvb + 131072 + frag_off(n, kk8, 256);
  } else if (v < 32768u){         // Wo (256x256)
    unsigned u = v-24576u, n = u>>5, kk8 = u&31u;
    sp = Wo + (size_t)u*8; dp = Wob + frag_off(n, kk8, 256);
  } else if (v < 65536u){         // W1 (1024x256)
    unsigned u = v-32768u, n = u>>5, kk8 = u&31u;
    sp = W1 + (size_t)u*8; dp = W1b + frag_off(n, kk8, 256);
  } else {                        // W2 (256x1024)
    unsigned u = v-65536u, n = u>>7, kk8 = u&127u;
    sp = W2 + (size_t)u*8; dp = W2b + frag_off(n, kk8, 1024);
  }
  float4 a = *(const float4*)sp, b = *(const float4*)(sp+4);
  short8v o;
  o[0]=(short)f2bf(a.x*sc); o[1]=(short)f2bf(a.y*sc); o[2]=(short)f2bf(a.z*sc); o[3]=(short)f2bf(a.w*sc);
  o[4]=(short)f2bf(b.x*sc); o[5]=(short)f2bf(b.y*sc); o[6]=(short)f2bf(b.z*sc); o[7]=(short)f2bf(b.w*sc);
  *(short8v*)dp = o;
}

// ---------------- generic MFMA GEMM: C[M][N] = A[M][KTOT] @ W[N][KTOT]^T (+bias, epilogue) ----------------
// W is fragment-major (coalesced 1KB wave loads). tile: M=64 x N=128 (4 waves, each 64x32).
// AF32=1: A read from fp32 (Af) and converted during staging.
// EPI: 0 = qkv -> Q,K row-major bf16 + V transposed bf16; 1 = +resid(f32) -> f32;
//      4 = +resid(bf16) -> bf16
template<int KTOT, int EPI, int AF32>
__global__ __launch_bounds__(256) void gemm_kernel(
    const us* __restrict__ A, const float* __restrict__ Af,
    const us* __restrict__ W,
    const float* __restrict__ bias0, const float* __restrict__ bias1, const float* __restrict__ bias2,
    const float* __restrict__ resid, const us* __restrict__ residb,
    us* __restrict__ outb, us* __restrict__ outv, float* __restrict__ outf){
  __shared__ us Asl[64*AS];
  const int t = threadIdx.x, l = t&63, wv = t>>6;
  const int lx = l&15, lw = l>>4;
  const int m0 = blockIdx.y*64;
  const int n0 = blockIdx.x*128 + wv*32;

  f32x4 acc[4][2];
  #pragma unroll
  for(int mb=0;mb<4;mb++)
    #pragma unroll
    for(int nb=0;nb<2;nb++) acc[mb][nb] = (f32x4){0.f,0.f,0.f,0.f};

  for (int kc = 0; kc < KTOT; kc += 256){
    __syncthreads();
    if (AF32){
      #pragma unroll
      for (int it=0; it<16; it++){
        int idx = it*256 + t;          // 4096 float4 units: 64 rows x 64
        int r = idx>>6, c = idx&63;
        float4 v = *(const float4*)(Af + (size_t)(m0+r)*KTOT + kc + c*4);
        short4v o4 = { (short)f2bf(v.x),(short)f2bf(v.y),(short)f2bf(v.z),(short)f2bf(v.w) };
        *(short4v*)&Asl[r*AS + c*4] = o4;
      }
    } else {
      #pragma unroll
      for (int it=0; it<8; it++){
        int idx = it*256 + t;          // 2048 16B-units: 64 rows x 32
        int r = idx>>5, c = idx&31;
        *(short8v*)&Asl[r*AS + c*8] = *(const short8v*)(A + (size_t)(m0+r)*KTOT + kc + c*8);
      }
    }
    __syncthreads();
    short8v bf[2][8];
    #pragma unroll
    for (int nb=0; nb<2; nb++)
      #pragma unroll
      for (int ks=0; ks<8; ks++)
        bf[nb][ks] = *(const short8v*)(W + (size_t)(n0 + nb*16)*KTOT + kc*16 + ks*512 + l*8);
    #pragma unroll
    for (int ks=0; ks<8; ks++){
      short8v af[4];
      #pragma unroll
      for (int mb=0; mb<4; mb++)
        af[mb] = *(const short8v*)&Asl[(mb*16+lx)*AS + ks*32 + 8*lw];
      #pragma unroll
      for (int mb=0; mb<4; mb++){
        acc[mb][0] = __builtin_amdgcn_mfma_f32_16x16x32_bf16(af[mb], bf[0][ks], acc[mb][0], 0,0,0);
        acc[mb][1] = __builtin_amdgcn_mfma_f32_16x16x32_bf16(af[mb], bf[1][ks], acc[mb][1], 0,0,0);
      }
    }
  }
  // epilogue: lane l, reg r -> m = m0 + mb*16 + 4*lw + r, n = n0 + nb*16 + lx
  const int mr0 = m0 + 4*lw;
  #pragma unroll
  for (int nb=0; nb<2; nb++){
    int n = n0 + nb*16 + lx;
    if (EPI == 0){
      int seg = n >> 8, nn = n & 255;
      const float* bp = (seg==0) ? bias0 : (seg==1) ? bias1 : bias2;
      float bb = bp[nn];
      if (seg < 2){
        us* op = outb + (size_t)seg*((size_t)NM*ND) + nn;
        #pragma unroll
        for (int mb=0; mb<4; mb++)
          #pragma unroll
          for (int r=0; r<4; r++)
            op[(size_t)(mr0 + mb*16 + r)*ND] = f2bf(acc[mb][nb][r] + bb);
      } else {   // V: write transposed Vt[b][h][d][s]
        int hh = nn >> 5, dd = nn & 31;
        int bidx = mr0 >> 11;           // batch (uniform per block)
        int s0 = mr0 & 2047;
        us* vp = outv + (((size_t)bidx*NH + hh)*NHD + dd)*NS;
        #pragma unroll
        for (int mb=0; mb<4; mb++){
          short4v v4;
          #pragma unroll
          for (int r=0; r<4; r++) v4[r] = (short)f2bf(acc[mb][nb][r] + bb);
          *(short4v*)(vp + s0 + mb*16) = v4;
        }
      }
    } else if (EPI == 1){
      float bb = bias0[n];
      #pragma unroll
      for (int mb=0; mb<4; mb++)
        #pragma unroll
        for (int r=0; r<4; r++){
          size_t off = (size_t)(mr0 + mb*16 + r)*ND + n;
          outf[off] = acc[mb][nb][r] + bb + resid[off];
        }
    } else {   // EPI 4: +resid(bf16) -> bf16
      float bb = bias0[n];
      #pragma unroll
      for (int mb=0; mb<4; mb++)
        #pragma unroll
        for (int r=0; r<4; r++){
          size_t off = (size_t)(mr0 + mb*16 + r)*ND + n;
          outb[off] = f2bf(acc[mb][nb][r] + bb + bf2f(residb[off]));
        }
    }
  }
}

// ---------------- ffn1 wide: M=64 x N=256 per block (4 waves, each 64x64), gelu -> bf16 ----------------
// W fragment-major; A (S2b) row-major via LDS; grid (4,128).
__global__ __launch_bounds__(256, 2) void ffn1w_kernel(
    const us* __restrict__ A, const us* __restrict__ W,
    const float* __restrict__ bias, us* __restrict__ FF){
  __shared__ us Asl[64*AS];
  const int t = threadIdx.x, l = t&63, wv = t>>6;
  const int lx = l&15, lw = l>>4;
  const int m0 = blockIdx.y*64;
  const int n0 = blockIdx.x*256 + wv*64;

  f32x4 acc[4][4];
  #pragma unroll
  for(int mb=0;mb<4;mb++)
    #pragma unroll
    for(int nb=0;nb<4;nb++) acc[mb][nb] = (f32x4){0.f,0.f,0.f,0.f};

  // K = 256: single chunk
  #pragma unroll
  for (int it=0; it<8; it++){
    int idx = it*256 + t;              // 2048 16B-units: 64 rows x 32
    int r = idx>>5, c = idx&31;
    *(short8v*)&Asl[r*AS + c*8] = *(const short8v*)(A + (size_t)(m0+r)*ND + c*8);
  }
  __syncthreads();
  #pragma unroll
  for (int ks=0; ks<8; ks++){
    short8v bf[4];
    #pragma unroll
    for (int nb=0; nb<4; nb++)
      bf[nb] = *(const short8v*)(W + (size_t)(n0 + nb*16)*ND + ks*512 + l*8);
    short8v af[4];
    #pragma unroll
    for (int mb=0; mb<4; mb++)
      af[mb] = *(const short8v*)&Asl[(mb*16+lx)*AS + ks*32 + 8*lw];
    #pragma unroll
    for (int mb=0; mb<4; mb++)
      #pragma unroll
      for (int nb=0; nb<4; nb++)
        acc[mb][nb] = __builtin_amdgcn_mfma_f32_16x16x32_bf16(af[mb], bf[nb], acc[mb][nb], 0,0,0);
  }
  const int mr0 = m0 + 4*lw;
  #pragma unroll
  for (int nb=0; nb<4; nb++){
    int n = n0 + nb*16 + lx;
    float bb = bias[n];
    #pragma unroll
    for (int mb=0; mb<4; mb++)
      #pragma unroll
      for (int r=0; r<4; r++){
        float x = acc[mb][nb][r] + bb;
        float g = 0.5f*x*(1.f + erff(x*0.70710678118654752f));
        FF[(size_t)(mr0 + mb*16 + r)*NFF + n] = f2bf(g);
      }
  }
}

// ---------------- LayerNorm, fp32 in -> bf16 out ----------------
__global__ __launch_bounds__(256) void ln_kernel(
    const float* __restrict__ Xin, const float* __restrict__ g, const float* __restrict__ be,
    us* __restrict__ outb){
  const int t = threadIdx.x, lane = t&63, wv = t>>6;
  const int m0 = blockIdx.x*16;
  #pragma unroll
  for(int rr=0; rr<4; rr++){
    int r = m0 + wv*4 + rr;
    const float* xr = Xin + (size_t)r*ND;
    float x[4]; float s=0.f,q=0.f;
    #pragma unroll
    for(int k=0;k<4;k++){ x[k]=xr[lane+64*k]; s+=x[k]; q+=x[k]*x[k]; }
    s = wsum(s); q = wsum(q);
    float mean = s*(1.f/ND), var = q*(1.f/ND)-mean*mean;
    float rstd = rsqrtf(var+1e-5f);
    #pragma unroll
    for(int k=0;k<4;k++){
      int col = lane+64*k;
      outb[(size_t)r*ND+col] = f2bf((x[k]-mean)*rstd*g[col] + be[col]);
    }
  }
}

// ---------------- LayerNorm, bf16 in -> fp32 out (final) ----------------
__global__ __launch_bounds__(256) void lnb_kernel(
    const us* __restrict__ Xin, const float* __restrict__ g, const float* __restrict__ be,
    float* __restrict__ outf){
  const int t = threadIdx.x, lane = t&63, wv = t>>6;
  const int m0 = blockIdx.x*16;
  #pragma unroll
  for(int rr=0; rr<4; rr++){
    int r = m0 + wv*4 + rr;
    const us* xr = Xin + (size_t)r*ND;
    float x[4]; float s=0.f,q=0.f;
    #pragma unroll
    for(int k=0;k<4;k++){ x[k]=bf2f(xr[lane+64*k]); s+=x[k]; q+=x[k]*x[k]; }
    s = wsum(s); q = wsum(q);
    float mean = s*(1.f/ND), var = q*(1.f/ND)-mean*mean;
    float rstd = rsqrtf(var+1e-5f);
    #pragma unroll
    for(int k=0;k<4;k++){
      int col = lane+64*k;
      outf[(size_t)r*ND+col] = (x[k]-mean)*rstd*g[col] + be[col];
    }
  }
}

// ---------------- attention tile body: lane-local P (permuted-V LDS), tree lsum ----------------
// V LDS layout per 32-key block: slot(16m+4a+b) = 8a+4m+b  (a=0..3,m=0..1,b=0..3).
// PV B-frag slot j at lane (lx,lw) needs key 32c+16(j>>2)+4lw+(j&3) == this lane's p[8c+j].
template<bool MASK>
__device__ __forceinline__ void attn_tile(
    const us* __restrict__ Kl, const us* __restrict__ Vl,
    const short8v qf, const int lx, const int lw, const int jt, const int qg,
    f32x4& acc0, f32x4& acc1, float& lsum){
  f32x4 s4[4];
  #pragma unroll
  for (int kb=0; kb<4; kb++){
    short8v kf = *(const short8v*)(Kl + (kb*16 + lx)*KPAD + 8*lw);
    f32x4 z = {0.f,0.f,0.f,0.f};
    s4[kb] = __builtin_amdgcn_mfma_f32_16x16x32_bf16(kf, qf, z, 0,0,0);
  }
  float p[16];
  #pragma unroll
  for (int kb=0; kb<4; kb++)
    #pragma unroll
    for (int r=0; r<4; r++){
      float x = exp2f(s4[kb][r]);
      if (MASK) x = ((jt + 16*kb + 4*lw + r) > qg) ? 0.f : x;
      p[kb*4+r] = x;
    }
  {
    float a0=p[0]+p[1],   a1=p[2]+p[3],   a2=p[4]+p[5],   a3=p[6]+p[7];
    float a4=p[8]+p[9],   a5=p[10]+p[11], a6=p[12]+p[13], a7=p[14]+p[15];
    float b0=a0+a1, b1=a2+a3, b2=a4+a5, b3=a6+a7;
    lsum += (b0+b1) + (b2+b3);
  }
  #pragma unroll
  for (int c=0; c<2; c++){
    unsigned w0,w1,w2,w3;
    asm("v_cvt_pk_bf16_f32 %0, %1, %2" : "=v"(w0) : "v"(p[8*c+0]), "v"(p[8*c+1]));
    asm("v_cvt_pk_bf16_f32 %0, %1, %2" : "=v"(w1) : "v"(p[8*c+2]), "v"(p[8*c+3]));
    asm("v_cvt_pk_bf16_f32 %0, %1, %2" : "=v"(w2) : "v"(p[8*c+4]), "v"(p[8*c+5]));
    asm("v_cvt_pk_bf16_f32 %0, %1, %2" : "=v"(w3) : "v"(p[8*c+6]), "v"(p[8*c+7]));
    union { unsigned u[4]; short8v v; } pu;
    pu.u[0]=w0; pu.u[1]=w1; pu.u[2]=w2; pu.u[3]=w3;
    short8v pf = pu.v;
    short8v aL = *(const short8v*)(Vl + (size_t)( lx    )*VSP + 32*c + 8*lw);
    short8v aH = *(const short8v*)(Vl + (size_t)(16+lx  )*VSP + 32*c + 8*lw);
    acc0 = __builtin_amdgcn_mfma_f32_16x16x32_bf16(aL, pf, acc0, 0,0,0);
    acc1 = __builtin_amdgcn_mfma_f32_16x16x32_bf16(aH, pf, acc1, 0,0,0);
  }
}

// ---------------- MFMA flash attention: dbuf LDS staging, 1 barrier/tile, lane-local P ----------------
__global__ __launch_bounds__(256) void attn_kernel(
    const us* __restrict__ Q, const us* __restrict__ K,
    const us* __restrict__ Vt, us* __restrict__ AO){
  __shared__ us Klds[2][64*KPAD];      // 2 x 5120 B
  __shared__ us Vs[2][32*VSP];         // 2 x 4608 B  (permuted slot layout)
  __shared__ us Ex[4][16*VTP];         // 4 x 2304 B  per-wave O-bounce (epilogue only)

  const int t = threadIdx.x, l = t & 63, wv = t >> 6;
  const int lx = l & 15, lw = l >> 4;
  const int bid = blockIdx.x;
  const int qtile = 31 - (bid >> 5);   // biggest query tiles first
  const int bh = bid & 31;
  const int b = bh >> 3, h = bh & 7;
  const int qbase = qtile*64 + wv*16;  // this wave's first query
  const int qg = qbase + lx;

  const us* Qg = Q + ((size_t)b*NS)*ND + h*NHD;
  const us* Kg = K + ((size_t)b*NS)*ND + h*NHD;
  const us* Vg = Vt + (size_t)bh*NHD*NS;

  short8v qf = *(const short8v*)(Qg + (size_t)(qbase + lx)*ND + 8*lw);

  f32x4 acc0 = {0.f,0.f,0.f,0.f}, acc1 = {0.f,0.f,0.f,0.f};
  float lsum = 0.f;

  const int kr = t >> 2, kp = t & 3;   // K staging: 64 rows x 4 b128 segs
  const int vd = t >> 3, vp = t & 7;   // V staging: 32 d-rows x 8 key-segs
  const int vS0 = 32*(vp>>2) + 16*(vp&1) + 4*((vp>>1)&1);   // permuted slot base
  const int jmax = qtile*64;           // final (masked) tile start

  // prologue: stage tile 0
  {
    short8v k0 = *(const short8v*)(Kg + (size_t)kr*ND + kp*8);
    short8v v0 = *(const short8v*)(Vg + (size_t)vd*NS + vp*8);
    *(short8v*)&Klds[0][kr*KPAD + kp*8] = k0;
    short4v lo = {v0[0],v0[1],v0[2],v0[3]}, hi = {v0[4],v0[5],v0[6],v0[7]};
    *(short4v*)&Vs[0][vd*VSP + vS0]     = lo;
    *(short4v*)&Vs[0][vd*VSP + vS0 + 8] = hi;
  }
  __syncthreads();

  int cur = 0;
  for (int jt = 0; jt < jmax; jt += 64){
    short8v kn = *(const short8v*)(Kg + (size_t)(jt + 64 + kr)*ND + kp*8);
    short8v vn = *(const short8v*)(Vg + (size_t)vd*NS + (jt + 64) + vp*8);
    attn_tile<false>(&Klds[cur][0], &Vs[cur][0], qf, lx, lw, jt, qg, acc0, acc1, lsum);
    *(short8v*)&Klds[cur^1][kr*KPAD + kp*8] = kn;
    short4v lo = {vn[0],vn[1],vn[2],vn[3]}, hi = {vn[4],vn[5],vn[6],vn[7]};
    *(short4v*)&Vs[cur^1][vd*VSP + vS0]     = lo;
    *(short4v*)&Vs[cur^1][vd*VSP + vS0 + 8] = hi;
    __syncthreads();
    cur ^= 1;
  }
  // final tile (diagonal): causal mask, no prefetch
  attn_tile<true>(&Klds[cur][0], &Vs[cur][0], qf, lx, lw, jmax, qg, acc0, acc1, lsum);

  // epilogue: normalize, bounce O^T->O through per-wave LDS, bf16 store
  float lt = lsum + __shfl_xor(lsum, 16);
  lt += __shfl_xor(lt, 32);
  float inv = 1.f / lt;
  float* ol = (float*)&Ex[wv][0];
  #pragma unroll
  for (int r=0;r<4;r++){
    ol[lx*36 +      4*lw + r] = acc0[r]*inv;
    ol[lx*36 + 16 + 4*lw + r] = acc1[r]*inv;
  }
  int rr = l >> 2, cc = l & 3;         // 16 rows x 4 chunks of 8
  const float* op8 = &ol[rr*36 + cc*8];
  short8v o8;
  #pragma unroll
  for (int j=0;j<8;j++) o8[j] = (short)f2bf(op8[j]);
  *(short8v*)(AO + ((size_t)(b*NS + qbase + rr))*ND + h*NHD + cc*8) = o8;
}

extern "C" void kernel_launch(void* const* d_in, const int* in_sizes, int n_in,
                              void* d_out, int out_size, void* d_ws, size_t ws_size,
                              hipStream_t stream){
  const float* src = (const float*)d_in[0];
  const float* Wq  = (const float*)d_in[1];
  const float* bq  = (const float*)d_in[2];
  const float* Wk  = (const float*)d_in[3];
  const float* bk  = (const float*)d_in[4];
  const float* Wv  = (const float*)d_in[5];
  const float* bv  = (const float*)d_in[6];
  const float* Wo  = (const float*)d_in[7];
  const float* bo  = (const float*)d_in[8];
  const float* W1  = (const float*)d_in[9];
  const float* b1  = (const float*)d_in[10];
  const float* W2  = (const float*)d_in[11];
  const float* b2  = (const float*)d_in[12];
  const float* g1  = (const float*)d_in[13];
  const float* be1 = (const float*)d_in[14];
  const float* g2  = (const float*)d_in[15];
  const float* be2 = (const float*)d_in[16];
  // len_m1 (d_in[17]) is redundant: the prefix-global mask is implied by causal.

  const size_t MB = 1048576;
  unsigned char* w8 = (unsigned char*)d_ws;
  us* Yb    = (us*)(w8 + 0);           // 4MB (pre-LN2, bf16); region free until ffn2
  us* Qb    = (us*)(w8 + 4*MB);        // 4MB, dead after attn
  us* Kb    = (us*)(w8 + 8*MB);
  us* Vtg   = (us*)(w8 + 12*MB);       // V transposed [b][h][d][s]
  us* AO    = (us*)(w8 + 16*MB);
  us* S2b   = (us*)(w8 + 20*MB);       // LN1 out bf16 (ffn1 input + ffn2 residual)
  us* FF    = (us*)(w8 + 24*MB);       // 16MB
  us* Wqkvb = (us*)(w8 + 40*MB);       // 384KB  (fragment-major; Wq*QSCALE | Wk | Wv)
  us* Wob   = (us*)(w8 + 40*MB + 384*1024);
  us* W1b   = (us*)(w8 + 40*MB + 512*1024);
  us* W2b   = (us*)(w8 + 40*MB + 1024*1024);
  float* bqs   = (float*)(w8 + 40*MB + 1536*1024);
  float* S2pre = (float*)(w8 + 42*MB); // 8MB
  float* out = (float*)d_out;

  prep_kernel<<<385, 256, 0, stream>>>(Wq,Wk,Wv,Wo,W1,W2, bq, Wqkvb, Wob, W1b, W2b, bqs);
  gemm_kernel<256,0,1><<<dim3(6,128), 256, 0, stream>>>(nullptr, src, Wqkvb, bqs, bk, bv, nullptr, nullptr, Qb, Vtg, nullptr);
  attn_kernel<<<1024, 256, 0, stream>>>(Qb, Kb, Vtg, AO);
  gemm_kernel<256,1,0><<<dim3(2,128), 256, 0, stream>>>(AO, nullptr, Wob, bo, nullptr, nullptr, src, nullptr, nullptr, nullptr, S2pre);
  ln_kernel<<<NM/16, 256, 0, stream>>>(S2pre, g1, be1, S2b);
  ffn1w_kernel<<<dim3(4,128), 256, 0, stream>>>(S2b, W1b, b1, FF);
  gemm_kernel<1024,4,0><<<dim3(2,128), 256, 0, stream>>>(FF, nullptr, W2b, b2, nullptr, nullptr, nullptr, S2b, Yb, nullptr, nullptr);
  lnb_kernel<<<NM/16, 256, 0, stream>>>(Yb, g2, be2, out);
}

// Round 23
// 97.157 us; speedup vs baseline: 1.0931x; 1.0113x over previous
//
#include <hip/hip_runtime.h>
#include <math.h>

#define NB 4
#define NS 2048
#define ND 256
#define NH 8
#define NHD 32
#define NFF 1024
#define NM (NB*NS)   // 8192
#define KPAD 40      // K-tile LDS row stride (bf16)
#define VSP 72       // Vt-tile LDS row stride (bf16)
#define VTP 72       // Ex row stride (epilogue O-bounce)
#define AS 264       // gemm A-tile LDS row stride (bf16 elems)
// qkv Q pre-scale: (1/sqrt(32)) * log2(e)  -> softmax uses exp2, no max subtraction
#define QSCALE 0.2550181657f

typedef __attribute__((ext_vector_type(4))) short short4v;
typedef __attribute__((ext_vector_type(8))) short short8v;
typedef __attribute__((ext_vector_type(4))) float f32x4;
typedef unsigned short us;

__device__ __forceinline__ us f2bf(float f){
  union { float f; unsigned u; } c; c.f = f;
  unsigned u = c.u + 0x7fffu + ((c.u >> 16) & 1u);   // RNE
  return (us)(u >> 16);
}
__device__ __forceinline__ float bf2f(us u){
  union { unsigned u; float f; } c; c.u = ((unsigned)u) << 16; return c.f;
}

__device__ __forceinline__ float wsum(float v){
  #pragma unroll
  for(int o=32;o>0;o>>=1) v += __shfl_xor(v,o);
  return v;
}

// fragment-major W offset: W'[(n>>4)][k>>5][lane=lw*16+lx][8 elems]
__device__ __forceinline__ size_t frag_off(unsigned n, unsigned kk8, unsigned K){
  return (size_t)(n >> 4)*(16u*K) + (size_t)(kk8 >> 2)*512u + (size_t)(((kk8 & 3u)*16u + (n & 15u))*8u);
}

// ---------------- prep: weights fp32 -> bf16 fragment-major (Wq/bq pre-scaled) ----------------
__global__ __launch_bounds__(256) void prep_kernel(
    const float* __restrict__ Wq, const float* __restrict__ Wk, const float* __restrict__ Wv,
    const float* __restrict__ Wo, const float* __restrict__ W1, const float* __restrict__ W2,
    const float* __restrict__ bq,
    us* __restrict__ Wqkvb, us* __restrict__ Wob,
    us* __restrict__ W1b, us* __restrict__ W2b, float* __restrict__ bqs){
  unsigned bid = blockIdx.x;
  if (bid == 384){ bqs[threadIdx.x] = bq[threadIdx.x]*QSCALE; return; }
  unsigned v = bid*256u + threadIdx.x;     // 8-elem unit, 98304 total
  const float* sp; us* dp; float sc = 1.f;
  if (v < 8192u){                 // Wq (256x256)
    unsigned u = v, n = u>>5, kk8 = u&31u;
    sp = Wq + (size_t)u*8; dp = Wqkvb + frag_off(n, kk8, 256); sc = QSCALE;
  } else if (v < 16384u){         // Wk
    unsigned u = v-8192u, n = u>>5, kk8 = u&31u;
    sp = Wk + (size_t)u*8; dp = Wqkvb + 65536 + frag_off(n, kk8, 256);
  } else if (v < 24576u){         // Wv
    unsigned u = v-16384u, n = u>>5, kk8 = u&31u;
    sp = Wv + (size_t)u*8; dp = Wqkvb + 131072 + frag_off(n, kk8, 256);
  } else if (v < 32768u){         // Wo (256x256)
    unsigned u = v-24576u, n = u>>5, kk8 = u&31u;
    sp = Wo + (size_t)u*8; dp = Wob + frag_off(n, kk8, 256);
  } else if (v < 65536u){         // W1 (1024x256)
    unsigned u = v-32768u, n = u>>5, kk8 = u&31u;
    sp = W1 + (size_t)u*8; dp = W1b + frag_off(n, kk8, 256);
  } else {                        // W2 (256x1024)
    unsigned u = v-65536u, n = u>>7, kk8 = u&127u;
    sp = W2 + (size_t)u*8; dp = W2b + frag_off(n, kk8, 1024);
  }
  float4 a = *(const float4*)sp, b = *(const float4*)(sp+4);
  short8v o;
  o[0]=(short)f2bf(a.x*sc); o[1]=(short)f2bf(a.y*sc); o[2]=(short)f2bf(a.z*sc); o[3]=(short)f2bf(a.w*sc);
  o[4]=(short)f2bf(b.x*sc); o[5]=(short)f2bf(b.y*sc); o[6]=(short)f2bf(b.z*sc); o[7]=(short)f2bf(b.w*sc);
  *(short8v*)dp = o;
}

// ---------------- generic MFMA GEMM: C[M][N] = A[M][KTOT] @ W[N][KTOT]^T (+bias, epilogue) ----------------
// W is fragment-major (coalesced 1KB wave loads). tile: M=64 x N=128 (4 waves, each 64x32).
// AF32=1: A read from fp32 (Af) and converted during staging.
// EPI: 0 = qkv -> Q,K row-major bf16 + V transposed bf16; 1 = +resid(f32) -> f32;
//      4 = +resid(bf16) -> bf16;  5 = +resid(f32) -> bf16
template<int KTOT, int EPI, int AF32>
__global__ __launch_bounds__(256) void gemm_kernel(
    const us* __restrict__ A, const float* __restrict__ Af,
    const us* __restrict__ W,
    const float* __restrict__ bias0, const float* __restrict__ bias1, const float* __restrict__ bias2,
    const float* __restrict__ resid, const us* __restrict__ residb,
    us* __restrict__ outb, us* __restrict__ outv, float* __restrict__ outf){
  __shared__ us Asl[64*AS];
  const int t = threadIdx.x, l = t&63, wv = t>>6;
  const int lx = l&15, lw = l>>4;
  const int m0 = blockIdx.y*64;
  const int n0 = blockIdx.x*128 + wv*32;

  f32x4 acc[4][2];
  #pragma unroll
  for(int mb=0;mb<4;mb++)
    #pragma unroll
    for(int nb=0;nb<2;nb++) acc[mb][nb] = (f32x4){0.f,0.f,0.f,0.f};

  for (int kc = 0; kc < KTOT; kc += 256){
    __syncthreads();
    if (AF32){
      #pragma unroll
      for (int it=0; it<16; it++){
        int idx = it*256 + t;          // 4096 float4 units: 64 rows x 64
        int r = idx>>6, c = idx&63;
        float4 v = *(const float4*)(Af + (size_t)(m0+r)*KTOT + kc + c*4);
        short4v o4 = { (short)f2bf(v.x),(short)f2bf(v.y),(short)f2bf(v.z),(short)f2bf(v.w) };
        *(short4v*)&Asl[r*AS + c*4] = o4;
      }
    } else {
      #pragma unroll
      for (int it=0; it<8; it++){
        int idx = it*256 + t;          // 2048 16B-units: 64 rows x 32
        int r = idx>>5, c = idx&31;
        *(short8v*)&Asl[r*AS + c*8] = *(const short8v*)(A + (size_t)(m0+r)*KTOT + kc + c*8);
      }
    }
    __syncthreads();
    short8v bf[2][8];
    #pragma unroll
    for (int nb=0; nb<2; nb++)
      #pragma unroll
      for (int ks=0; ks<8; ks++)
        bf[nb][ks] = *(const short8v*)(W + (size_t)(n0 + nb*16)*KTOT + kc*16 + ks*512 + l*8);
    #pragma unroll
    for (int ks=0; ks<8; ks++){
      short8v af[4];
      #pragma unroll
      for (int mb=0; mb<4; mb++)
        af[mb] = *(const short8v*)&Asl[(mb*16+lx)*AS + ks*32 + 8*lw];
      #pragma unroll
      for (int mb=0; mb<4; mb++){
        acc[mb][0] = __builtin_amdgcn_mfma_f32_16x16x32_bf16(af[mb], bf[0][ks], acc[mb][0], 0,0,0);
        acc[mb][1] = __builtin_amdgcn_mfma_f32_16x16x32_bf16(af[mb], bf[1][ks], acc[mb][1], 0,0,0);
      }
    }
  }
  // epilogue: lane l, reg r -> m = m0 + mb*16 + 4*lw + r, n = n0 + nb*16 + lx
  const int mr0 = m0 + 4*lw;
  #pragma unroll
  for (int nb=0; nb<2; nb++){
    int n = n0 + nb*16 + lx;
    if (EPI == 0){
      int seg = n >> 8, nn = n & 255;
      const float* bp = (seg==0) ? bias0 : (seg==1) ? bias1 : bias2;
      float bb = bp[nn];
      if (seg < 2){
        us* op = outb + (size_t)seg*((size_t)NM*ND) + nn;
        #pragma unroll
        for (int mb=0; mb<4; mb++)
          #pragma unroll
          for (int r=0; r<4; r++)
            op[(size_t)(mr0 + mb*16 + r)*ND] = f2bf(acc[mb][nb][r] + bb);
      } else {   // V: write transposed Vt[b][h][d][s]
        int hh = nn >> 5, dd = nn & 31;
        int bidx = mr0 >> 11;           // batch (uniform per block)
        int s0 = mr0 & 2047;
        us* vp = outv + (((size_t)bidx*NH + hh)*NHD + dd)*NS;
        #pragma unroll
        for (int mb=0; mb<4; mb++){
          short4v v4;
          #pragma unroll
          for (int r=0; r<4; r++) v4[r] = (short)f2bf(acc[mb][nb][r] + bb);
          *(short4v*)(vp + s0 + mb*16) = v4;
        }
      }
    } else if (EPI == 1){
      float bb = bias0[n];
      #pragma unroll
      for (int mb=0; mb<4; mb++)
        #pragma unroll
        for (int r=0; r<4; r++){
          size_t off = (size_t)(mr0 + mb*16 + r)*ND + n;
          outf[off] = acc[mb][nb][r] + bb + resid[off];
        }
    } else if (EPI == 5){   // +resid(f32) -> bf16
      float bb = bias0[n];
      #pragma unroll
      for (int mb=0; mb<4; mb++)
        #pragma unroll
        for (int r=0; r<4; r++){
          size_t off = (size_t)(mr0 + mb*16 + r)*ND + n;
          outb[off] = f2bf(acc[mb][nb][r] + bb + resid[off]);
        }
    } else {   // EPI 4: +resid(bf16) -> bf16
      float bb = bias0[n];
      #pragma unroll
      for (int mb=0; mb<4; mb++)
        #pragma unroll
        for (int r=0; r<4; r++){
          size_t off = (size_t)(mr0 + mb*16 + r)*ND + n;
          outb[off] = f2bf(acc[mb][nb][r] + bb + bf2f(residb[off]));
        }
    }
  }
}

// ---------------- ffn1 wide: M=64 x N=256 per block (4 waves, each 64x64), gelu -> bf16 ----------------
// W fragment-major; A (S2b) row-major via LDS; grid (4,128).
__global__ __launch_bounds__(256, 2) void ffn1w_kernel(
    const us* __restrict__ A, const us* __restrict__ W,
    const float* __restrict__ bias, us* __restrict__ FF){
  __shared__ us Asl[64*AS];
  const int t = threadIdx.x, l = t&63, wv = t>>6;
  const int lx = l&15, lw = l>>4;
  const int m0 = blockIdx.y*64;
  const int n0 = blockIdx.x*256 + wv*64;

  f32x4 acc[4][4];
  #pragma unroll
  for(int mb=0;mb<4;mb++)
    #pragma unroll
    for(int nb=0;nb<4;nb++) acc[mb][nb] = (f32x4){0.f,0.f,0.f,0.f};

  // K = 256: single chunk
  #pragma unroll
  for (int it=0; it<8; it++){
    int idx = it*256 + t;              // 2048 16B-units: 64 rows x 32
    int r = idx>>5, c = idx&31;
    *(short8v*)&Asl[r*AS + c*8] = *(const short8v*)(A + (size_t)(m0+r)*ND + c*8);
  }
  __syncthreads();
  #pragma unroll
  for (int ks=0; ks<8; ks++){
    short8v bf[4];
    #pragma unroll
    for (int nb=0; nb<4; nb++)
      bf[nb] = *(const short8v*)(W + (size_t)(n0 + nb*16)*ND + ks*512 + l*8);
    short8v af[4];
    #pragma unroll
    for (int mb=0; mb<4; mb++)
      af[mb] = *(const short8v*)&Asl[(mb*16+lx)*AS + ks*32 + 8*lw];
    #pragma unroll
    for (int mb=0; mb<4; mb++)
      #pragma unroll
      for (int nb=0; nb<4; nb++)
        acc[mb][nb] = __builtin_amdgcn_mfma_f32_16x16x32_bf16(af[mb], bf[nb], acc[mb][nb], 0,0,0);
  }
  const int mr0 = m0 + 4*lw;
  #pragma unroll
  for (int nb=0; nb<4; nb++){
    int n = n0 + nb*16 + lx;
    float bb = bias[n];
    #pragma unroll
    for (int mb=0; mb<4; mb++)
      #pragma unroll
      for (int r=0; r<4; r++){
        float x = acc[mb][nb][r] + bb;
        float g = 0.5f*x*(1.f + erff(x*0.70710678118654752f));
        FF[(size_t)(mr0 + mb*16 + r)*NFF + n] = f2bf(g);
      }
  }
}

// ---------------- LayerNorm, bf16 in -> bf16 out ----------------
__global__ __launch_bounds__(256) void lnbb_kernel(
    const us* __restrict__ Xin, const float* __restrict__ g, const float* __restrict__ be,
    us* __restrict__ outb){
  const int t = threadIdx.x, lane = t&63, wv = t>>6;
  const int m0 = blockIdx.x*16;
  #pragma unroll
  for(int rr=0; rr<4; rr++){
    int r = m0 + wv*4 + rr;
    const us* xr = Xin + (size_t)r*ND;
    float x[4]; float s=0.f,q=0.f;
    #pragma unroll
    for(int k=0;k<4;k++){ x[k]=bf2f(xr[lane+64*k]); s+=x[k]; q+=x[k]*x[k]; }
    s = wsum(s); q = wsum(q);
    float mean = s*(1.f/ND), var = q*(1.f/ND)-mean*mean;
    float rstd = rsqrtf(var+1e-5f);
    #pragma unroll
    for(int k=0;k<4;k++){
      int col = lane+64*k;
      outb[(size_t)r*ND+col] = f2bf((x[k]-mean)*rstd*g[col] + be[col]);
    }
  }
}

// ---------------- LayerNorm, bf16 in -> fp32 out (final) ----------------
__global__ __launch_bounds__(256) void lnb_kernel(
    const us* __restrict__ Xin, const float* __restrict__ g, const float* __restrict__ be,
    float* __restrict__ outf){
  const int t = threadIdx.x, lane = t&63, wv = t>>6;
  const int m0 = blockIdx.x*16;
  #pragma unroll
  for(int rr=0; rr<4; rr++){
    int r = m0 + wv*4 + rr;
    const us* xr = Xin + (size_t)r*ND;
    float x[4]; float s=0.f,q=0.f;
    #pragma unroll
    for(int k=0;k<4;k++){ x[k]=bf2f(xr[lane+64*k]); s+=x[k]; q+=x[k]*x[k]; }
    s = wsum(s); q = wsum(q);
    float mean = s*(1.f/ND), var = q*(1.f/ND)-mean*mean;
    float rstd = rsqrtf(var+1e-5f);
    #pragma unroll
    for(int k=0;k<4;k++){
      int col = lane+64*k;
      outf[(size_t)r*ND+col] = (x[k]-mean)*rstd*g[col] + be[col];
    }
  }
}

// ---------------- attention tile body: lane-local P (permuted-V LDS), tree lsum ----------------
// V LDS layout per 32-key block: slot(16m+4a+b) = 8a+4m+b  (a=0..3,m=0..1,b=0..3).
// PV B-frag slot j at lane (lx,lw) needs key 32c+16(j>>2)+4lw+(j&3) == this lane's p[8c+j].
template<bool MASK>
__device__ __forceinline__ void attn_tile(
    const us* __restrict__ Kl, const us* __restrict__ Vl,
    const short8v qf, const int lx, const int lw, const int jt, const int qg,
    f32x4& acc0, f32x4& acc1, float& lsum){
  f32x4 s4[4];
  #pragma unroll
  for (int kb=0; kb<4; kb++){
    short8v kf = *(const short8v*)(Kl + (kb*16 + lx)*KPAD + 8*lw);
    f32x4 z = {0.f,0.f,0.f,0.f};
    s4[kb] = __builtin_amdgcn_mfma_f32_16x16x32_bf16(kf, qf, z, 0,0,0);
  }
  float p[16];
  #pragma unroll
  for (int kb=0; kb<4; kb++)
    #pragma unroll
    for (int r=0; r<4; r++){
      float x = exp2f(s4[kb][r]);
      if (MASK) x = ((jt + 16*kb + 4*lw + r) > qg) ? 0.f : x;
      p[kb*4+r] = x;
    }
  {
    float a0=p[0]+p[1],   a1=p[2]+p[3],   a2=p[4]+p[5],   a3=p[6]+p[7];
    float a4=p[8]+p[9],   a5=p[10]+p[11], a6=p[12]+p[13], a7=p[14]+p[15];
    float b0=a0+a1, b1=a2+a3, b2=a4+a5, b3=a6+a7;
    lsum += (b0+b1) + (b2+b3);
  }
  #pragma unroll
  for (int c=0; c<2; c++){
    unsigned w0,w1,w2,w3;
    asm("v_cvt_pk_bf16_f32 %0, %1, %2" : "=v"(w0) : "v"(p[8*c+0]), "v"(p[8*c+1]));
    asm("v_cvt_pk_bf16_f32 %0, %1, %2" : "=v"(w1) : "v"(p[8*c+2]), "v"(p[8*c+3]));
    asm("v_cvt_pk_bf16_f32 %0, %1, %2" : "=v"(w2) : "v"(p[8*c+4]), "v"(p[8*c+5]));
    asm("v_cvt_pk_bf16_f32 %0, %1, %2" : "=v"(w3) : "v"(p[8*c+6]), "v"(p[8*c+7]));
    union { unsigned u[4]; short8v v; } pu;
    pu.u[0]=w0; pu.u[1]=w1; pu.u[2]=w2; pu.u[3]=w3;
    short8v pf = pu.v;
    short8v aL = *(const short8v*)(Vl + (size_t)( lx    )*VSP + 32*c + 8*lw);
    short8v aH = *(const short8v*)(Vl + (size_t)(16+lx  )*VSP + 32*c + 8*lw);
    acc0 = __builtin_amdgcn_mfma_f32_16x16x32_bf16(aL, pf, acc0, 0,0,0);
    acc1 = __builtin_amdgcn_mfma_f32_16x16x32_bf16(aH, pf, acc1, 0,0,0);
  }
}

// ---------------- MFMA flash attention: dbuf LDS staging, 1 barrier/tile, lane-local P ----------------
__global__ __launch_bounds__(256) void attn_kernel(
    const us* __restrict__ Q, const us* __restrict__ K,
    const us* __restrict__ Vt, us* __restrict__ AO){
  __shared__ us Klds[2][64*KPAD];      // 2 x 5120 B
  __shared__ us Vs[2][32*VSP];         // 2 x 4608 B  (permuted slot layout)
  __shared__ us Ex[4][16*VTP];         // 4 x 2304 B  per-wave O-bounce (epilogue only)

  const int t = threadIdx.x, l = t & 63, wv = t >> 6;
  const int lx = l & 15, lw = l >> 4;
  const int bid = blockIdx.x;
  const int qtile = 31 - (bid >> 5);   // biggest query tiles first
  const int bh = bid & 31;
  const int b = bh >> 3, h = bh & 7;
  const int qbase = qtile*64 + wv*16;  // this wave's first query
  const int qg = qbase + lx;

  const us* Qg = Q + ((size_t)b*NS)*ND + h*NHD;
  const us* Kg = K + ((size_t)b*NS)*ND + h*NHD;
  const us* Vg = Vt + (size_t)bh*NHD*NS;

  short8v qf = *(const short8v*)(Qg + (size_t)(qbase + lx)*ND + 8*lw);

  f32x4 acc0 = {0.f,0.f,0.f,0.f}, acc1 = {0.f,0.f,0.f,0.f};
  float lsum = 0.f;

  const int kr = t >> 2, kp = t & 3;   // K staging: 64 rows x 4 b128 segs
  const int vd = t >> 3, vp = t & 7;   // V staging: 32 d-rows x 8 key-segs
  const int vS0 = 32*(vp>>2) + 16*(vp&1) + 4*((vp>>1)&1);   // permuted slot base
  const int jmax = qtile*64;           // final (masked) tile start

  // prologue: stage tile 0
  {
    short8v k0 = *(const short8v*)(Kg + (size_t)kr*ND + kp*8);
    short8v v0 = *(const short8v*)(Vg + (size_t)vd*NS + vp*8);
    *(short8v*)&Klds[0][kr*KPAD + kp*8] = k0;
    short4v lo = {v0[0],v0[1],v0[2],v0[3]}, hi = {v0[4],v0[5],v0[6],v0[7]};
    *(short4v*)&Vs[0][vd*VSP + vS0]     = lo;
    *(short4v*)&Vs[0][vd*VSP + vS0 + 8] = hi;
  }
  __syncthreads();

  int cur = 0;
  for (int jt = 0; jt < jmax; jt += 64){
    short8v kn = *(const short8v*)(Kg + (size_t)(jt + 64 + kr)*ND + kp*8);
    short8v vn = *(const short8v*)(Vg + (size_t)vd*NS + (jt + 64) + vp*8);
    attn_tile<false>(&Klds[cur][0], &Vs[cur][0], qf, lx, lw, jt, qg, acc0, acc1, lsum);
    *(short8v*)&Klds[cur^1][kr*KPAD + kp*8] = kn;
    short4v lo = {vn[0],vn[1],vn[2],vn[3]}, hi = {vn[4],vn[5],vn[6],vn[7]};
    *(short4v*)&Vs[cur^1][vd*VSP + vS0]     = lo;
    *(short4v*)&Vs[cur^1][vd*VSP + vS0 + 8] = hi;
    __syncthreads();
    cur ^= 1;
  }
  // final tile (diagonal): causal mask, no prefetch
  attn_tile<true>(&Klds[cur][0], &Vs[cur][0], qf, lx, lw, jmax, qg, acc0, acc1, lsum);

  // epilogue: normalize, bounce O^T->O through per-wave LDS, bf16 store
  float lt = lsum + __shfl_xor(lsum, 16);
  lt += __shfl_xor(lt, 32);
  float inv = 1.f / lt;
  float* ol = (float*)&Ex[wv][0];
  #pragma unroll
  for (int r=0;r<4;r++){
    ol[lx*36 +      4*lw + r] = acc0[r]*inv;
    ol[lx*36 + 16 + 4*lw + r] = acc1[r]*inv;
  }
  int rr = l >> 2, cc = l & 3;         // 16 rows x 4 chunks of 8
  const float* op8 = &ol[rr*36 + cc*8];
  short8v o8;
  #pragma unroll
  for (int j=0;j<8;j++) o8[j] = (short)f2bf(op8[j]);
  *(short8v*)(AO + ((size_t)(b*NS + qbase + rr))*ND + h*NHD + cc*8) = o8;
}

extern "C" void kernel_launch(void* const* d_in, const int* in_sizes, int n_in,
                              void* d_out, int out_size, void* d_ws, size_t ws_size,
                              hipStream_t stream){
  const float* src = (const float*)d_in[0];
  const float* Wq  = (const float*)d_in[1];
  const float* bq  = (const float*)d_in[2];
  const float* Wk  = (const float*)d_in[3];
  const float* bk  = (const float*)d_in[4];
  const float* Wv  = (const float*)d_in[5];
  const float* bv  = (const float*)d_in[6];
  const float* Wo  = (const float*)d_in[7];
  const float* bo  = (const float*)d_in[8];
  const float* W1  = (const float*)d_in[9];
  const float* b1  = (const float*)d_in[10];
  const float* W2  = (const float*)d_in[11];
  const float* b2  = (const float*)d_in[12];
  const float* g1  = (const float*)d_in[13];
  const float* be1 = (const float*)d_in[14];
  const float* g2  = (const float*)d_in[15];
  const float* be2 = (const float*)d_in[16];
  // len_m1 (d_in[17]) is redundant: the prefix-global mask is implied by causal.

  const size_t MB = 1048576;
  unsigned char* w8 = (unsigned char*)d_ws;
  us* Yb    = (us*)(w8 + 0);           // 4MB (pre-LN2, bf16)
  us* Qb    = (us*)(w8 + 4*MB);        // 4MB, dead after attn
  us* Kb    = (us*)(w8 + 8*MB);
  us* Vtg   = (us*)(w8 + 12*MB);       // V transposed [b][h][d][s]
  us* AO    = (us*)(w8 + 16*MB);
  us* S2b   = (us*)(w8 + 20*MB);       // LN1 out bf16 (ffn1 input + ffn2 residual)
  us* FF    = (us*)(w8 + 24*MB);       // 16MB
  us* Wqkvb = (us*)(w8 + 40*MB);       // 384KB  (fragment-major; Wq*QSCALE | Wk | Wv)
  us* Wob   = (us*)(w8 + 40*MB + 384*1024);
  us* W1b   = (us*)(w8 + 40*MB + 512*1024);
  us* W2b   = (us*)(w8 + 40*MB + 1024*1024);
  float* bqs = (float*)(w8 + 40*MB + 1536*1024);
  us* Y1b   = (us*)(w8 + 42*MB);       // 4MB (pre-LN1 sum, bf16)
  float* out = (float*)d_out;

  prep_kernel<<<385, 256, 0, stream>>>(Wq,Wk,Wv,Wo,W1,W2, bq, Wqkvb, Wob, W1b, W2b, bqs);
  gemm_kernel<256,0,1><<<dim3(6,128), 256, 0, stream>>>(nullptr, src, Wqkvb, bqs, bk, bv, nullptr, nullptr, Qb, Vtg, nullptr);
  attn_kernel<<<1024, 256, 0, stream>>>(Qb, Kb, Vtg, AO);
  gemm_kernel<256,5,0><<<dim3(2,128), 256, 0, stream>>>(AO, nullptr, Wob, bo, nullptr, nullptr, src, nullptr, Y1b, nullptr, nullptr);
  lnbb_kernel<<<NM/16, 256, 0, stream>>>(Y1b, g1, be1, S2b);
  ffn1w_kernel<<<dim3(4,128), 256, 0, stream>>>(S2b, W1b, b1, FF);
  gemm_kernel<1024,4,0><<<dim3(2,128), 256, 0, stream>>>(FF, nullptr, W2b, b2, nullptr, nullptr, nullptr, S2b, Yb, nullptr, nullptr);
  lnb_kernel<<<NM/16, 256, 0, stream>>>(Yb, g2, be2, out);
}